// Round 4
// baseline (199.811 us; speedup 1.0000x reference)
//
#include <hip/hip_runtime.h>

typedef __bf16 bf16x8 __attribute__((ext_vector_type(8)));
typedef float  f32x4  __attribute__((ext_vector_type(4)));
typedef unsigned short us4 __attribute__((ext_vector_type(4)));

#define B_      64
#define C_      128
#define M_      4096
#define KCHUNK  8
#define KC      (M_ / KCHUNK)   // 512
#define BK      256             // k-floats per LDS slab: 1 KB contiguous per row visit
#define NSLAB   (KC / BK)       // 2
#define LSTR    264             // bf16 elems per LDS row (256 + 8 pad); 528 B, 16B-aligned rows

__device__ __forceinline__ unsigned short f2bf(float f) {
  unsigned u = __builtin_bit_cast(unsigned, f);
  return (unsigned short)((u + 0x8000u) >> 16);   // round-half-up; margin vs threshold is ample
}
__device__ __forceinline__ float bf2f(unsigned short h) {
  unsigned u = ((unsigned)h) << 16;
  return __builtin_bit_cast(float, u);
}

// 512 threads = 8 waves.
// Load/stage map: wave w -> rows w*16..w*16+15; lane = lr*4+q; thread owns row (w*16+lr),
//   float4 index (q + 4*j), j=0..15  => each load INSTRUCTION covers 16 rows x 64 B full lines,
//   and a wave's 16 instructions sweep 1 KB sequentially over the SAME 16 rows (DRAM page friendly).
// MFMA map: wave w -> output rows (w>>2)*64..+63, cols (w&3)*32..+31 (4x2 16x16 tiles).
__global__ __launch_bounds__(512, 4) void covpool_main(
    const float* __restrict__ x, unsigned short* __restrict__ Gp, float* __restrict__ Sp) {
  __shared__ unsigned short As[C_ * LSTR];   // 66 KiB, single buffer -> 2 blocks/CU

  const int tid  = threadIdx.x;
  const int b    = blockIdx.x >> 3;
  const int ch   = blockIdx.x & 7;

  const int lane = tid & 63;
  const int wave = tid >> 6;

  // staging coords
  const int lr   = lane >> 2;            // 0..15
  const int q    = lane & 3;             // 0..3
  const int row  = wave * 16 + lr;       // 0..127
  const float* rowbase = x + ((size_t)(b * C_ + row) * M_) + (size_t)ch * KC;

  // MFMA coords
  const int row0 = (wave >> 2) << 6;     // 0 or 64
  const int col0 = (wave & 3) << 5;      // 0,32,64,96
  const int lrow = lane & 15;
  const int quad = lane >> 4;

  f32x4 acc[4][2];
#pragma unroll
  for (int i = 0; i < 4; ++i)
#pragma unroll
    for (int j = 0; j < 2; ++j)
      acc[i][j] = (f32x4){0.f, 0.f, 0.f, 0.f};

  float sum = 0.f;

#pragma unroll
  for (int s = 0; s < NSLAB; ++s) {
    const float4* rp = (const float4*)(rowbase + s * BK);
    float4 L[8];
    // ---- load phase: 2 batches of 8 dwordx4, all in flight before first use ----
#pragma unroll
    for (int jj = 0; jj < 8; ++jj) L[jj] = rp[q + 4 * jj];
#pragma unroll
    for (int jj = 0; jj < 8; ++jj) {
      float4 v = L[jj];
      sum += (v.x + v.y) + (v.z + v.w);
      us4 h = { f2bf(v.x), f2bf(v.y), f2bf(v.z), f2bf(v.w) };
      *(__shared__ us4*)&As[row * LSTR + (q + 4 * jj) * 4] = h;
    }
#pragma unroll
    for (int jj = 0; jj < 8; ++jj) L[jj] = rp[q + 4 * (8 + jj)];
#pragma unroll
    for (int jj = 0; jj < 8; ++jj) {
      float4 v = L[jj];
      sum += (v.x + v.y) + (v.z + v.w);
      us4 h = { f2bf(v.x), f2bf(v.y), f2bf(v.z), f2bf(v.w) };
      *(__shared__ us4*)&As[row * LSTR + (q + 4 * (8 + jj)) * 4] = h;
    }
    __syncthreads();
    // ---- compute phase: 8 k-steps over the 256-wide slab ----
#pragma unroll
    for (int ks = 0; ks < 8; ++ks) {
      const int koff = ks * 32 + quad * 8;
      bf16x8 af[4], bfr[2];
#pragma unroll
      for (int i = 0; i < 4; ++i)
        af[i] = *(const __shared__ bf16x8*)&As[(row0 + i * 16 + lrow) * LSTR + koff];
#pragma unroll
      for (int j = 0; j < 2; ++j)
        bfr[j] = *(const __shared__ bf16x8*)&As[(col0 + j * 16 + lrow) * LSTR + koff];
#pragma unroll
      for (int i = 0; i < 4; ++i)
#pragma unroll
        for (int j = 0; j < 2; ++j)
          acc[i][j] = __builtin_amdgcn_mfma_f32_16x16x32_bf16(af[i], bfr[j], acc[i][j], 0, 0, 0);
    }
    __syncthreads();   // protect LDS before next slab's overwrite
  }

  // partial G (bf16), layout [ch][b][128][128]
  unsigned short* gout = Gp + (((size_t)ch * B_ + b) << 14);
#pragma unroll
  for (int i = 0; i < 4; ++i)
#pragma unroll
    for (int j = 0; j < 2; ++j)
#pragma unroll
      for (int rr = 0; rr < 4; ++rr)
        gout[(size_t)(row0 + i * 16 + quad * 4 + rr) * C_ + (col0 + j * 16 + lrow)] =
            f2bf(acc[i][j][rr]);

  // row sums: 4 lanes (q=0..3) share row; combine in-wave
  sum += __shfl_xor(sum, 1); sum += __shfl_xor(sum, 2);
  if (q == 0) {
    float* sout = Sp + (((size_t)ch * B_ + b) << 7);
    sout[row] = sum;
  }
}

__global__ __launch_bounds__(256) void covpool_fix(
    const unsigned short* __restrict__ Gp, const float* __restrict__ Sp,
    float* __restrict__ y) {
  const int idx = (blockIdx.x * 256 + threadIdx.x) * 4;   // 4 outputs/thread
  const int bb  = idx >> 14;
  const int rem = idx & 16383;
  const int cc  = rem >> 7;
  const int dd  = rem & 127;    // multiple of 4
  float g0 = 0.f, g1 = 0.f, g2 = 0.f, g3 = 0.f, sc = 0.f;
  float4 sd = {0.f, 0.f, 0.f, 0.f};
#pragma unroll
  for (int ch = 0; ch < KCHUNK; ++ch) {
    ushort4 gv = *(const ushort4*)&Gp[(((size_t)ch * B_ + bb) << 14) + rem];
    g0 += bf2f(gv.x); g1 += bf2f(gv.y); g2 += bf2f(gv.z); g3 += bf2f(gv.w);
    const float* sp = Sp + (((size_t)ch * B_ + bb) << 7);
    sc += sp[cc];
    float4 s4 = *(const float4*)&sp[dd];
    sd.x += s4.x; sd.y += s4.y; sd.z += s4.z; sd.w += s4.w;
  }
  const float invM = 1.f / (float)M_;
  const float scm = sc * invM;
  float4 out = { g0 * invM - scm * (sd.x * invM), g1 * invM - scm * (sd.y * invM),
                 g2 * invM - scm * (sd.z * invM), g3 * invM - scm * (sd.w * invM) };
  *(float4*)&y[idx] = out;
}

extern "C" void kernel_launch(void* const* d_in, const int* in_sizes, int n_in,
                              void* d_out, int out_size, void* d_ws, size_t ws_size,
                              hipStream_t stream) {
  const float* x = (const float*)d_in[0];
  float* out = (float*)d_out;
  unsigned short* wsG = (unsigned short*)d_ws;                // 8*64*16384 bf16 = 16.8 MB
  float* wsS = (float*)(wsG + (size_t)KCHUNK * B_ * C_ * C_); // 8*64*128 fp32 = 256 KB
  covpool_main<<<dim3(B_ * KCHUNK), dim3(512), 0, stream>>>(x, wsG, wsS);
  covpool_fix<<<dim3((B_ * C_ * C_) / 1024), dim3(256), 0, stream>>>(wsG, wsS, out);
}

// Round 5
// 199.081 us; speedup vs baseline: 1.0037x; 1.0037x over previous
//
#include <hip/hip_runtime.h>

typedef __bf16 bf16x8 __attribute__((ext_vector_type(8)));
typedef float  f32x4  __attribute__((ext_vector_type(4)));
typedef unsigned short us4 __attribute__((ext_vector_type(4)));

#define B_      64
#define C_      128
#define M_      4096
#define KCHUNK  8
#define KC      (M_ / KCHUNK)   // 512
#define BK      256             // k-floats per LDS slab: 1 KB contiguous per row visit
#define NSLAB   (KC / BK)       // 2
#define LSTR    264             // bf16 elems per LDS row (256 + 8 pad); 528 B, 16B-aligned rows

__device__ __forceinline__ unsigned short f2bf(float f) {
  unsigned u = __builtin_bit_cast(unsigned, f);
  return (unsigned short)((u + 0x8000u) >> 16);   // round-half-up; margin vs threshold is ample
}
__device__ __forceinline__ float bf2f(unsigned short h) {
  unsigned u = ((unsigned)h) << 16;
  return __builtin_bit_cast(float, u);
}

// 512 threads = 8 waves.
// Block swizzle: b = blk&63, ch = ((blk>>6)+blk)&7.  This decorrelates the k-chunk
// column (address bits 11-13, the L2/L3 slice-select bits) from the XCD a block runs
// on: under either round-robin (XCD=blk%8) or chunked dispatch, each XCD's resident
// blocks cover ALL 8 chunk columns instead of camping on one.  R2-R4 all had ch==blk&7
// == XCD, so every XCD hammered 1/8 of the cache slices -> ~2 TB/s ceiling regardless
// of pipelining structure.
// Load/stage map: wave w -> rows w*16..w*16+15; lane = lr*4+q; thread owns row (w*16+lr),
//   float4 index (q + 4*j), j=0..15  => each load instr covers 16 rows x 64 B full lines.
// MFMA map: wave w -> output rows (w>>2)*64..+63, cols (w&3)*32..+31 (4x2 16x16 tiles).
__global__ __launch_bounds__(512, 4) void covpool_main(
    const float* __restrict__ x, unsigned short* __restrict__ Gp, float* __restrict__ Sp) {
  __shared__ unsigned short As[C_ * LSTR];   // 66 KiB, single buffer -> 2 blocks/CU

  const int raw  = blockIdx.x;
  const int b    = raw & 63;
  const int ch   = ((raw >> 6) + raw) & 7;

  const int tid  = threadIdx.x;
  const int lane = tid & 63;
  const int wave = tid >> 6;

  // staging coords
  const int lr   = lane >> 2;            // 0..15
  const int q    = lane & 3;             // 0..3
  const int row  = wave * 16 + lr;       // 0..127
  const float* rowbase = x + ((size_t)(b * C_ + row) * M_) + (size_t)ch * KC;

  // MFMA coords
  const int row0 = (wave >> 2) << 6;     // 0 or 64
  const int col0 = (wave & 3) << 5;      // 0,32,64,96
  const int lrow = lane & 15;
  const int quad = lane >> 4;

  f32x4 acc[4][2];
#pragma unroll
  for (int i = 0; i < 4; ++i)
#pragma unroll
    for (int j = 0; j < 2; ++j)
      acc[i][j] = (f32x4){0.f, 0.f, 0.f, 0.f};

  float sum = 0.f;

#pragma unroll
  for (int s = 0; s < NSLAB; ++s) {
    const float4* rp = (const float4*)(rowbase + s * BK);
    float4 L[8];
    // ---- load phase: 2 batches of 8 dwordx4, all in flight before first use ----
#pragma unroll
    for (int jj = 0; jj < 8; ++jj) L[jj] = rp[q + 4 * jj];
#pragma unroll
    for (int jj = 0; jj < 8; ++jj) {
      float4 v = L[jj];
      sum += (v.x + v.y) + (v.z + v.w);
      us4 h = { f2bf(v.x), f2bf(v.y), f2bf(v.z), f2bf(v.w) };
      *(__shared__ us4*)&As[row * LSTR + (q + 4 * jj) * 4] = h;
    }
#pragma unroll
    for (int jj = 0; jj < 8; ++jj) L[jj] = rp[q + 4 * (8 + jj)];
#pragma unroll
    for (int jj = 0; jj < 8; ++jj) {
      float4 v = L[jj];
      sum += (v.x + v.y) + (v.z + v.w);
      us4 h = { f2bf(v.x), f2bf(v.y), f2bf(v.z), f2bf(v.w) };
      *(__shared__ us4*)&As[row * LSTR + (q + 4 * (8 + jj)) * 4] = h;
    }
    __syncthreads();
    // ---- compute phase: 8 k-steps over the 256-wide slab ----
#pragma unroll
    for (int ks = 0; ks < 8; ++ks) {
      const int koff = ks * 32 + quad * 8;
      bf16x8 af[4], bfr[2];
#pragma unroll
      for (int i = 0; i < 4; ++i)
        af[i] = *(const __shared__ bf16x8*)&As[(row0 + i * 16 + lrow) * LSTR + koff];
#pragma unroll
      for (int j = 0; j < 2; ++j)
        bfr[j] = *(const __shared__ bf16x8*)&As[(col0 + j * 16 + lrow) * LSTR + koff];
#pragma unroll
      for (int i = 0; i < 4; ++i)
#pragma unroll
        for (int j = 0; j < 2; ++j)
          acc[i][j] = __builtin_amdgcn_mfma_f32_16x16x32_bf16(af[i], bfr[j], acc[i][j], 0, 0, 0);
    }
    __syncthreads();   // protect LDS before next slab's overwrite
  }

  // partial G (bf16), layout [ch][b][128][128]
  unsigned short* gout = Gp + (((size_t)ch * B_ + b) << 14);
#pragma unroll
  for (int i = 0; i < 4; ++i)
#pragma unroll
    for (int j = 0; j < 2; ++j)
#pragma unroll
      for (int rr = 0; rr < 4; ++rr)
        gout[(size_t)(row0 + i * 16 + quad * 4 + rr) * C_ + (col0 + j * 16 + lrow)] =
            f2bf(acc[i][j][rr]);

  // row sums: 4 lanes (q=0..3) share row; combine in-wave
  sum += __shfl_xor(sum, 1); sum += __shfl_xor(sum, 2);
  if (q == 0) {
    float* sout = Sp + (((size_t)ch * B_ + b) << 7);
    sout[row] = sum;
  }
}

__global__ __launch_bounds__(256) void covpool_fix(
    const unsigned short* __restrict__ Gp, const float* __restrict__ Sp,
    float* __restrict__ y) {
  const int idx = (blockIdx.x * 256 + threadIdx.x) * 4;   // 4 outputs/thread
  const int bb  = idx >> 14;
  const int rem = idx & 16383;
  const int cc  = rem >> 7;
  const int dd  = rem & 127;    // multiple of 4
  float g0 = 0.f, g1 = 0.f, g2 = 0.f, g3 = 0.f, sc = 0.f;
  float4 sd = {0.f, 0.f, 0.f, 0.f};
#pragma unroll
  for (int ch = 0; ch < KCHUNK; ++ch) {
    ushort4 gv = *(const ushort4*)&Gp[(((size_t)ch * B_ + bb) << 14) + rem];
    g0 += bf2f(gv.x); g1 += bf2f(gv.y); g2 += bf2f(gv.z); g3 += bf2f(gv.w);
    const float* sp = Sp + (((size_t)ch * B_ + bb) << 7);
    sc += sp[cc];
    float4 s4 = *(const float4*)&sp[dd];
    sd.x += s4.x; sd.y += s4.y; sd.z += s4.z; sd.w += s4.w;
  }
  const float invM = 1.f / (float)M_;
  const float scm = sc * invM;
  float4 out = { g0 * invM - scm * (sd.x * invM), g1 * invM - scm * (sd.y * invM),
                 g2 * invM - scm * (sd.z * invM), g3 * invM - scm * (sd.w * invM) };
  *(float4*)&y[idx] = out;
}

extern "C" void kernel_launch(void* const* d_in, const int* in_sizes, int n_in,
                              void* d_out, int out_size, void* d_ws, size_t ws_size,
                              hipStream_t stream) {
  const float* x = (const float*)d_in[0];
  float* out = (float*)d_out;
  unsigned short* wsG = (unsigned short*)d_ws;                // 8*64*16384 bf16 = 16.8 MB
  float* wsS = (float*)(wsG + (size_t)KCHUNK * B_ * C_ * C_); // 8*64*128 fp32 = 256 KB
  covpool_main<<<dim3(B_ * KCHUNK), dim3(512), 0, stream>>>(x, wsG, wsS);
  covpool_fix<<<dim3((B_ * C_ * C_) / 1024), dim3(256), 0, stream>>>(wsG, wsS, out);
}